// Round 1
// baseline (235.902 us; speedup 1.0000x reference)
//
#include <hip/hip_runtime.h>
#include <stdint.h>

typedef unsigned short u16;
typedef short bf16x8 __attribute__((ext_vector_type(8)));
typedef unsigned short u16x4 __attribute__((ext_vector_type(4)));
typedef float f32x4 __attribute__((ext_vector_type(4)));

#define NROW 4096
#define LDW 72  // LDS row stride (in u16) for the 64x64 W^T tile; 144B: 8B/16B aligned

// round-to-nearest-even float -> bf16 bits
__device__ __forceinline__ u16 f2bf(float f) {
  uint32_t u = __float_as_uint(f);
  u = (u + 0x7fffu + ((u >> 16) & 1u)) >> 16;
  return (u16)u;
}

__device__ __forceinline__ f32x4 mfma16(bf16x8 a, bf16x8 b, f32x4 c) {
  return __builtin_amdgcn_mfma_f32_16x16x32_bf16(a, b, c, 0, 0, 0);
}

__device__ __forceinline__ bf16x8 ld8(const u16* p) {
  return *reinterpret_cast<const bf16x8*>(p);
}

// weight2: d < r/2 -> 1 ; r/2 <= d < r -> (1-((2d-r)/r)^2)^3 ; else 0
__device__ __forceinline__ float wfun2(float d, float r, float half, float invr) {
  float t = (2.f * d - r) * invr;
  float b = 1.f - t * t;
  float w = b * b * b;
  return d < half ? 1.f : (d < r ? w : 0.f);
}

// ---------------- prep: sq[i], xb (bf16 row-major), xT (bf16 col-major) ----------------
__global__ void prep_kernel(const float* __restrict__ x, u16* __restrict__ xb,
                            u16* __restrict__ xT, float* __restrict__ sq) {
  int row = blockIdx.x * 4 + (threadIdx.x >> 6);
  int lane = threadIdx.x & 63;
  float v = x[row * 64 + lane];
  u16 b = f2bf(v);
  xb[row * 64 + lane] = b;
  xT[lane * NROW + row] = b;
  float s = v * v;
#pragma unroll
  for (int o = 1; o < 64; o <<= 1) s += __shfl_xor(s, o);
  if (lane == 0) sq[row] = s;
}

// ---------------- pass1: max over clamped d2, into 64 slots ----------------
__global__ __launch_bounds__(256) void pass1_max(const u16* __restrict__ xb,
                                                 const float* __restrict__ sq,
                                                 float* __restrict__ maxslots) {
  int w = threadIdx.x >> 6, lane = threadIdx.x & 63;
  int l16 = lane & 15, quad = lane >> 4;
  int ti = blockIdx.x & 63, tj = blockIdx.x >> 6;
  int i0 = ti * 64 + w * 16, j0 = tj * 64;
  bf16x8 a0 = ld8(xb + (i0 + l16) * 64 + quad * 8);
  bf16x8 a1 = ld8(xb + (i0 + l16) * 64 + 32 + quad * 8);
  float sqi[4];
#pragma unroll
  for (int r = 0; r < 4; ++r) sqi[r] = sq[i0 + quad * 4 + r];
  float m = 0.f;
#pragma unroll
  for (int jt = 0; jt < 4; ++jt) {
    int jr = j0 + jt * 16 + l16;
    bf16x8 b0 = ld8(xb + jr * 64 + quad * 8);
    bf16x8 b1 = ld8(xb + jr * 64 + 32 + quad * 8);
    f32x4 g = {0.f, 0.f, 0.f, 0.f};
    g = mfma16(a0, b0, g);
    g = mfma16(a1, b1, g);
    float sj = sq[jr];
#pragma unroll
    for (int r = 0; r < 4; ++r) m = fmaxf(m, sqi[r] + sj - 2.f * g[r]);
  }
  m = fmaxf(m, 0.f);
#pragma unroll
  for (int o = 1; o < 64; o <<= 1) m = fmaxf(m, __shfl_xor(m, o));
  if (lane == 0) atomicMax((int*)&maxslots[blockIdx.x & 63], __float_as_int(m));
}

// ---------------- pass2: alpha weights + mu numerator / s_alpha ----------------
__global__ __launch_bounds__(256) void pass2_kernel(
    const u16* __restrict__ xb, const u16* __restrict__ xT, const float* __restrict__ sq,
    const float* __restrict__ maxslots, const float* __restrict__ r0in,
    float* __restrict__ mu_num, float* __restrict__ s_alpha) {
  __shared__ u16 ldsw[64 * LDW];
  const int tid = threadIdx.x, w = tid >> 6, lane = tid & 63;
  const int l16 = lane & 15, quad = lane >> 4;
  const int j0 = blockIdx.x * 64;
  const int ibase = blockIdx.y * 512;

  float md = 0.f;
#pragma unroll
  for (int k = 0; k < 64; ++k) md = fmaxf(md, maxslots[k]);
  const float r0 = fminf(r0in[0], sqrtf(md));
  const float r0sq = r0 * r0;
  const float invr0sq = 1.f / r0sq;

  float sqj[4];
  bf16x8 xj[4][2];
#pragma unroll
  for (int jt = 0; jt < 4; ++jt) {
    int jr = j0 + jt * 16 + l16;
    sqj[jt] = sq[jr];
    xj[jt][0] = ld8(xb + jr * 64 + quad * 8);
    xj[jt][1] = ld8(xb + jr * 64 + 32 + quad * 8);
  }
  f32x4 zero4 = {0.f, 0.f, 0.f, 0.f};
  f32x4 acc[4];
#pragma unroll
  for (int pt = 0; pt < 4; ++pt) acc[pt] = zero4;
  float sa[4] = {0.f, 0.f, 0.f, 0.f};

  for (int s = 0; s < 8; ++s) {
    const int ib = ibase + s * 64;
    const int ir = ib + w * 16;
    bf16x8 a0 = ld8(xb + (ir + l16) * 64 + quad * 8);
    bf16x8 a1 = ld8(xb + (ir + l16) * 64 + 32 + quad * 8);
    float sqi[4];
#pragma unroll
    for (int r = 0; r < 4; ++r) sqi[r] = sq[ir + quad * 4 + r];
#pragma unroll
    for (int jt = 0; jt < 4; ++jt) {
      f32x4 g = zero4;
      g = mfma16(a0, xj[jt][0], g);
      g = mfma16(a1, xj[jt][1], g);
      u16x4 pk;
#pragma unroll
      for (int r = 0; r < 4; ++r) {
        float d2 = fmaxf(sqi[r] + sqj[jt] - 2.f * g[r], 0.f);
        float w1 = 0.f;
        if (d2 < r0sq) {
          float b = 1.f - d2 * invr0sq;
          w1 = b * b * b;
        }
        sa[jt] += w1;
        pk[r] = f2bf(w1);
      }
      *reinterpret_cast<u16x4*>(&ldsw[(jt * 16 + l16) * LDW + w * 16 + quad * 4]) = pk;
    }
    __syncthreads();
    bf16x8 aw0 = *reinterpret_cast<const bf16x8*>(&ldsw[(w * 16 + l16) * LDW + quad * 8]);
    bf16x8 aw1 = *reinterpret_cast<const bf16x8*>(&ldsw[(w * 16 + l16) * LDW + 32 + quad * 8]);
#pragma unroll
    for (int pt = 0; pt < 4; ++pt) {
      const u16* xp = xT + (pt * 16 + l16) * NROW + ib + quad * 8;
      acc[pt] = mfma16(aw0, ld8(xp), acc[pt]);
      acc[pt] = mfma16(aw1, ld8(xp + 32), acc[pt]);
    }
    __syncthreads();
  }
#pragma unroll
  for (int pt = 0; pt < 4; ++pt)
#pragma unroll
    for (int r = 0; r < 4; ++r)
      atomicAdd(&mu_num[(j0 + w * 16 + quad * 4 + r) * 64 + pt * 16 + l16], acc[pt][r]);
#pragma unroll
  for (int jt = 0; jt < 4; ++jt) {
    float v = sa[jt];
    v += __shfl_xor(v, 16);
    v += __shfl_xor(v, 32);
    if (lane < 16) atomicAdd(&s_alpha[j0 + jt * 16 + lane], v);
  }
}

// ---------------- finish_mu: U = x - mu_num/s_alpha (NaN->x), Ub bf16, ||U||^2, t ----------------
__global__ void finish_mu_kernel(const float* __restrict__ x, const float* __restrict__ mu_num,
                                 const float* __restrict__ s_alpha, u16* __restrict__ ub,
                                 float* __restrict__ un2, float* __restrict__ tvec) {
  int row = blockIdx.x * 4 + (threadIdx.x >> 6);
  int lane = threadIdx.x & 63;
  float xv = x[row * 64 + lane];
  float m = mu_num[row * 64 + lane] / s_alpha[row];
  if (m != m) m = xv;
  float U = xv - m;
  ub[row * 64 + lane] = f2bf(U);
  float a = U * U;
  float b = xv * U;
#pragma unroll
  for (int o = 1; o < 64; o <<= 1) {
    a += __shfl_xor(a, o);
    b += __shfl_xor(b, o);
  }
  if (lane == 0) {
    un2[row] = a;
    tvec[row] = b;
  }
}

// ---------------- pass3: beta weights + e_Z numerator / s_beta ----------------
__global__ __launch_bounds__(256) void pass3_kernel(
    const u16* __restrict__ xb, const u16* __restrict__ xT, const u16* __restrict__ ub,
    const float* __restrict__ sq, const float* __restrict__ tvec, const float* __restrict__ un2,
    const float* __restrict__ maxslots, const float* __restrict__ r1in,
    const float* __restrict__ r2in, float* __restrict__ ez_num, float* __restrict__ s_beta) {
  __shared__ u16 ldsw[64 * LDW];
  const int tid = threadIdx.x, w = tid >> 6, lane = tid & 63;
  const int l16 = lane & 15, quad = lane >> 4;
  const int j0 = blockIdx.x * 64;
  const int ibase = blockIdx.y * 512;

  float md = 0.f;
#pragma unroll
  for (int k = 0; k < 64; ++k) md = fmaxf(md, maxslots[k]);
  const float mdist = sqrtf(md);
  const float r1 = fminf(r1in[0], mdist);
  const float r2 = fminf(r2in[0], mdist);
  const float h1 = 0.5f * r1, h2 = 0.5f * r2;
  const float inv1 = 1.f / r1, inv2 = 1.f / r2;

  float sqj[4], tj[4], u2j[4];
  bf16x8 xj[4][2], uj[4][2];
#pragma unroll
  for (int jt = 0; jt < 4; ++jt) {
    int jr = j0 + jt * 16 + l16;
    sqj[jt] = sq[jr];
    tj[jt] = tvec[jr];
    u2j[jt] = un2[jr];
    xj[jt][0] = ld8(xb + jr * 64 + quad * 8);
    xj[jt][1] = ld8(xb + jr * 64 + 32 + quad * 8);
    uj[jt][0] = ld8(ub + jr * 64 + quad * 8);
    uj[jt][1] = ld8(ub + jr * 64 + 32 + quad * 8);
  }
  f32x4 zero4 = {0.f, 0.f, 0.f, 0.f};
  f32x4 acc[4];
#pragma unroll
  for (int pt = 0; pt < 4; ++pt) acc[pt] = zero4;
  float sb[4] = {0.f, 0.f, 0.f, 0.f};

  for (int s = 0; s < 8; ++s) {
    const int ib = ibase + s * 64;
    const int ir = ib + w * 16;
    bf16x8 a0 = ld8(xb + (ir + l16) * 64 + quad * 8);
    bf16x8 a1 = ld8(xb + (ir + l16) * 64 + 32 + quad * 8);
    float sqi[4];
#pragma unroll
    for (int r = 0; r < 4; ++r) sqi[r] = sq[ir + quad * 4 + r];
#pragma unroll
    for (int jt = 0; jt < 4; ++jt) {
      f32x4 gxx = zero4, gxu = zero4;
      gxx = mfma16(a0, xj[jt][0], gxx);
      gxx = mfma16(a1, xj[jt][1], gxx);
      gxu = mfma16(a0, uj[jt][0], gxu);
      gxu = mfma16(a1, uj[jt][1], gxu);
      u16x4 pk;
#pragma unroll
      for (int r = 0; r < 4; ++r) {
        float d2 = fmaxf(sqi[r] + sqj[jt] - 2.f * gxx[r], 0.f);
        float c = gxu[r] - tj[jt];
        float du2 = fmaxf(c * c * u2j[jt], 1e-6f);
        float dv = sqrtf(fmaxf(d2 - du2, 1e-6f));
        float du = sqrtf(du2);
        float wv = wfun2(dv, r1, h1, inv1) * wfun2(du, r2, h2, inv2);
        sb[jt] += wv;
        pk[r] = f2bf(wv);
      }
      *reinterpret_cast<u16x4*>(&ldsw[(jt * 16 + l16) * LDW + w * 16 + quad * 4]) = pk;
    }
    __syncthreads();
    bf16x8 aw0 = *reinterpret_cast<const bf16x8*>(&ldsw[(w * 16 + l16) * LDW + quad * 8]);
    bf16x8 aw1 = *reinterpret_cast<const bf16x8*>(&ldsw[(w * 16 + l16) * LDW + 32 + quad * 8]);
#pragma unroll
    for (int pt = 0; pt < 4; ++pt) {
      const u16* xp = xT + (pt * 16 + l16) * NROW + ib + quad * 8;
      acc[pt] = mfma16(aw0, ld8(xp), acc[pt]);
      acc[pt] = mfma16(aw1, ld8(xp + 32), acc[pt]);
    }
    __syncthreads();
  }
#pragma unroll
  for (int pt = 0; pt < 4; ++pt)
#pragma unroll
    for (int r = 0; r < 4; ++r)
      atomicAdd(&ez_num[(j0 + w * 16 + quad * 4 + r) * 64 + pt * 16 + l16], acc[pt][r]);
#pragma unroll
  for (int jt = 0; jt < 4; ++jt) {
    float v = sb[jt];
    v += __shfl_xor(v, 16);
    v += __shfl_xor(v, 32);
    if (lane < 16) atomicAdd(&s_beta[j0 + jt * 16 + lane], v);
  }
}

// ---------------- finish: e_Z = ez_num / s_beta, NaN -> x ----------------
__global__ void finish_kernel(const float* __restrict__ x, const float* __restrict__ ez_num,
                              const float* __restrict__ s_beta, float* __restrict__ out) {
  int row = blockIdx.x * 4 + (threadIdx.x >> 6);
  int lane = threadIdx.x & 63;
  float xv = x[row * 64 + lane];
  float v = ez_num[row * 64 + lane] / s_beta[row];
  if (v != v) v = xv;
  out[row * 64 + lane] = v;
}

extern "C" void kernel_launch(void* const* d_in, const int* in_sizes, int n_in,
                              void* d_out, int out_size, void* d_ws, size_t ws_size,
                              hipStream_t stream) {
  (void)in_sizes; (void)n_in; (void)out_size;
  const float* x = (const float*)d_in[0];
  const float* r0 = (const float*)d_in[1];
  const float* r1 = (const float*)d_in[2];
  const float* r2 = (const float*)d_in[3];
  float* out = (float*)d_out;
  char* ws = (char*)d_ws;

  // workspace layout
  u16* xb = (u16*)(ws);                          // 512 KB
  u16* xT = (u16*)(ws + (512 << 10));            // 512 KB
  u16* ub = (u16*)(ws + (1024 << 10));           // 512 KB
  float* sq = (float*)(ws + (1536 << 10));       // 16 KB
  float* tv = (float*)(ws + (1552 << 10));       // 16 KB
  float* u2 = (float*)(ws + (1568 << 10));       // 16 KB
  char* zbase = ws + (1584 << 10);               // zeroed region:
  float* maxslots = (float*)zbase;               //   1 KB (64 slots + pad)
  float* s_alpha = (float*)(zbase + 1024);       //   16 KB
  float* s_beta = (float*)(zbase + 1024 + (16 << 10));  // 16 KB
  float* mu_num = (float*)(zbase + 1024 + (32 << 10));  // 1 MB
  float* ez_num = (float*)(zbase + 1024 + (32 << 10) + (1 << 20));  // 1 MB
  size_t zbytes = 1024 + (size_t)(32 << 10) + (size_t)(2 << 20);
  if (ws_size < (size_t)(1584 << 10) + zbytes) return;  // loud failure if ws too small

  hipMemsetAsync(zbase, 0, zbytes, stream);
  prep_kernel<<<1024, 256, 0, stream>>>(x, xb, xT, sq);
  pass1_max<<<4096, 256, 0, stream>>>(xb, sq, maxslots);
  pass2_kernel<<<dim3(64, 8), 256, 0, stream>>>(xb, xT, sq, maxslots, r0, mu_num, s_alpha);
  finish_mu_kernel<<<1024, 256, 0, stream>>>(x, mu_num, s_alpha, ub, u2, tv);
  pass3_kernel<<<dim3(64, 8), 256, 0, stream>>>(xb, xT, ub, sq, tv, u2, maxslots, r1, r2,
                                                ez_num, s_beta);
  finish_kernel<<<1024, 256, 0, stream>>>(x, ez_num, s_beta, out);
}

// Round 2
// 184.699 us; speedup vs baseline: 1.2772x; 1.2772x over previous
//
#include <hip/hip_runtime.h>
#include <stdint.h>

typedef unsigned short u16;
typedef short bf16x8 __attribute__((ext_vector_type(8)));
typedef unsigned short u16x4 __attribute__((ext_vector_type(4)));
typedef float f32x4 __attribute__((ext_vector_type(4)));

#define NROW 4096
#define LDW 72        // LDS row stride (u16) for 64x64 W^T tile
#define SLICE 262144  // 4096*64 floats per partial slice
#define NSPLIT 16     // split-k over i

// round-to-nearest-even float -> bf16 bits
__device__ __forceinline__ u16 f2bf(float f) {
  uint32_t u = __float_as_uint(f);
  u = (u + 0x7fffu + ((u >> 16) & 1u)) >> 16;
  return (u16)u;
}

__device__ __forceinline__ f32x4 mfma16(bf16x8 a, bf16x8 b, f32x4 c) {
  return __builtin_amdgcn_mfma_f32_16x16x32_bf16(a, b, c, 0, 0, 0);
}

__device__ __forceinline__ bf16x8 ld8(const u16* p) {
  return *reinterpret_cast<const bf16x8*>(p);
}

__device__ __forceinline__ float wfun2(float d, float r, float half, float invr) {
  float t = (2.f * d - r) * invr;
  float b = 1.f - t * t;
  float w = b * b * b;
  return d < half ? 1.f : (d < r ? w : 0.f);
}

// ---------------- prep: sq[i], xb (bf16 row-major), xT (bf16 col-major, LDS transpose) ----
__global__ __launch_bounds__(256) void prep_kernel(const float* __restrict__ x,
                                                   u16* __restrict__ xb, u16* __restrict__ xT,
                                                   float* __restrict__ sq) {
  __shared__ u16 lt[64 * 68];  // [col][row_local], stride 68 -> 2-way bank (free)
  const int w = threadIdx.x >> 6, lane = threadIdx.x & 63;
  const int r0 = blockIdx.x * 64;
#pragma unroll
  for (int rr = 0; rr < 16; ++rr) {
    int rl = w * 16 + rr;
    int row = r0 + rl;
    float v = x[row * 64 + lane];
    u16 b = f2bf(v);
    xb[row * 64 + lane] = b;
    lt[lane * 68 + rl] = b;
    float s = v * v;
#pragma unroll
    for (int o = 1; o < 64; o <<= 1) s += __shfl_xor(s, o);
    if (lane == 0) sq[row] = s;
  }
  __syncthreads();
#pragma unroll
  for (int cc = 0; cc < 16; ++cc) {
    int c = w * 16 + cc;
    xT[c * NROW + r0 + lane] = lt[c * 68 + lane];  // 128B contiguous per wave
  }
}

// ---------------- pass1: max over clamped d2; 1 atomic per block, spread slots -----------
__global__ __launch_bounds__(256) void pass1_max(const u16* __restrict__ xb,
                                                 const float* __restrict__ sq,
                                                 float* __restrict__ maxslots) {
  __shared__ float red[4];
  int w = threadIdx.x >> 6, lane = threadIdx.x & 63;
  int l16 = lane & 15, quad = lane >> 4;
  int ti = blockIdx.x & 63, tj = blockIdx.x >> 6;
  int i0 = ti * 64 + w * 16, j0 = tj * 64;
  bf16x8 a0 = ld8(xb + (i0 + l16) * 64 + quad * 8);
  bf16x8 a1 = ld8(xb + (i0 + l16) * 64 + 32 + quad * 8);
  float sqi[4];
#pragma unroll
  for (int r = 0; r < 4; ++r) sqi[r] = sq[i0 + quad * 4 + r];
  float m = 0.f;
#pragma unroll
  for (int jt = 0; jt < 4; ++jt) {
    int jr = j0 + jt * 16 + l16;
    bf16x8 b0 = ld8(xb + jr * 64 + quad * 8);
    bf16x8 b1 = ld8(xb + jr * 64 + 32 + quad * 8);
    f32x4 g = {0.f, 0.f, 0.f, 0.f};
    g = mfma16(a0, b0, g);
    g = mfma16(a1, b1, g);
    float sj = sq[jr];
#pragma unroll
    for (int r = 0; r < 4; ++r) m = fmaxf(m, sqi[r] + sj - 2.f * g[r]);
  }
  m = fmaxf(m, 0.f);
#pragma unroll
  for (int o = 1; o < 64; o <<= 1) m = fmaxf(m, __shfl_xor(m, o));
  if (lane == 0) red[w] = m;
  __syncthreads();
  if (threadIdx.x == 0) {
    m = fmaxf(fmaxf(red[0], red[1]), fmaxf(red[2], red[3]));
    atomicMax((int*)&maxslots[ti * 16], __float_as_int(m));  // 64 slots, 64B apart
  }
}

// ---------------- pass2: alpha weights + mu numerator partials ----------------
__global__ __launch_bounds__(256) void pass2_kernel(
    const u16* __restrict__ xb, const u16* __restrict__ xT, const float* __restrict__ sq,
    const float* __restrict__ maxslots, const float* __restrict__ r0in,
    float* __restrict__ mu_part, float* __restrict__ s_part) {
  __shared__ u16 ldsw[64 * LDW];
  __shared__ float sred[4][64];
  const int tid = threadIdx.x, w = tid >> 6, lane = tid & 63;
  const int l16 = lane & 15, quad = lane >> 4;
  const int j0 = blockIdx.x * 64;
  const int ibase = blockIdx.y * 256;

  float md = 0.f;
#pragma unroll
  for (int k = 0; k < 64; ++k) md = fmaxf(md, maxslots[k * 16]);
  const float r0 = fminf(r0in[0], sqrtf(md));
  const float r0sq = r0 * r0;
  const float invr0sq = 1.f / r0sq;

  float sqj[4];
  bf16x8 xj[4][2];
#pragma unroll
  for (int jt = 0; jt < 4; ++jt) {
    int jr = j0 + jt * 16 + l16;
    sqj[jt] = sq[jr];
    xj[jt][0] = ld8(xb + jr * 64 + quad * 8);
    xj[jt][1] = ld8(xb + jr * 64 + 32 + quad * 8);
  }
  f32x4 zero4 = {0.f, 0.f, 0.f, 0.f};
  f32x4 acc[4];
#pragma unroll
  for (int pt = 0; pt < 4; ++pt) acc[pt] = zero4;
  float sa[4] = {0.f, 0.f, 0.f, 0.f};

  for (int s = 0; s < 4; ++s) {
    const int ib = ibase + s * 64;
    const int ir = ib + w * 16;
    bf16x8 a0 = ld8(xb + (ir + l16) * 64 + quad * 8);
    bf16x8 a1 = ld8(xb + (ir + l16) * 64 + 32 + quad * 8);
    float sqi[4];
#pragma unroll
    for (int r = 0; r < 4; ++r) sqi[r] = sq[ir + quad * 4 + r];
#pragma unroll
    for (int jt = 0; jt < 4; ++jt) {
      f32x4 g = zero4;
      g = mfma16(a0, xj[jt][0], g);
      g = mfma16(a1, xj[jt][1], g);
      u16x4 pk;
#pragma unroll
      for (int r = 0; r < 4; ++r) {
        float d2 = fmaxf(sqi[r] + sqj[jt] - 2.f * g[r], 0.f);
        float w1 = 0.f;
        if (d2 < r0sq) {
          float b = 1.f - d2 * invr0sq;
          w1 = b * b * b;
        }
        sa[jt] += w1;
        pk[r] = f2bf(w1);
      }
      *reinterpret_cast<u16x4*>(&ldsw[(jt * 16 + l16) * LDW + w * 16 + quad * 4]) = pk;
    }
    __syncthreads();
    bf16x8 aw0 = *reinterpret_cast<const bf16x8*>(&ldsw[(w * 16 + l16) * LDW + quad * 8]);
    bf16x8 aw1 = *reinterpret_cast<const bf16x8*>(&ldsw[(w * 16 + l16) * LDW + 32 + quad * 8]);
#pragma unroll
    for (int pt = 0; pt < 4; ++pt) {
      const u16* xp = xT + (pt * 16 + l16) * NROW + ib + quad * 8;
      acc[pt] = mfma16(aw0, ld8(xp), acc[pt]);
      acc[pt] = mfma16(aw1, ld8(xp + 32), acc[pt]);
    }
    __syncthreads();
  }
  // plain stores of this split's partial numerator
  float* mp = mu_part + (size_t)blockIdx.y * SLICE;
#pragma unroll
  for (int pt = 0; pt < 4; ++pt)
#pragma unroll
    for (int r = 0; r < 4; ++r)
      mp[(j0 + w * 16 + quad * 4 + r) * 64 + pt * 16 + l16] = acc[pt][r];
  // per-j partial denominators: quad-reduce, cross-wave via LDS, plain store
#pragma unroll
  for (int jt = 0; jt < 4; ++jt) {
    float v = sa[jt];
    v += __shfl_xor(v, 16);
    v += __shfl_xor(v, 32);
    if (lane < 16) sred[w][jt * 16 + lane] = v;
  }
  __syncthreads();
  if (tid < 64)
    s_part[blockIdx.y * NROW + j0 + tid] =
        sred[0][tid] + sred[1][tid] + sred[2][tid] + sred[3][tid];
}

// ---------------- finish_mu: reduce partials; U, ||U||^2, t ----------------
__global__ __launch_bounds__(256) void finish_mu_kernel(
    const float* __restrict__ x, const float* __restrict__ mu_part,
    const float* __restrict__ s_part, u16* __restrict__ ub, float* __restrict__ un2,
    float* __restrict__ tvec) {
  int row = blockIdx.x * 4 + (threadIdx.x >> 6);
  int lane = threadIdx.x & 63;
  float num = 0.f, den = 0.f;
#pragma unroll
  for (int y = 0; y < NSPLIT; ++y) {
    num += mu_part[(size_t)y * SLICE + row * 64 + lane];
    den += s_part[y * NROW + row];
  }
  float xv = x[row * 64 + lane];
  float m = num / den;
  if (m != m) m = xv;
  float U = xv - m;
  ub[row * 64 + lane] = f2bf(U);
  float a = U * U;
  float b = xv * U;
#pragma unroll
  for (int o = 1; o < 64; o <<= 1) {
    a += __shfl_xor(a, o);
    b += __shfl_xor(b, o);
  }
  if (lane == 0) {
    un2[row] = a;
    tvec[row] = b;
  }
}

// ---------------- pass3: beta weights + e_Z numerator partials ----------------
__global__ __launch_bounds__(256) void pass3_kernel(
    const u16* __restrict__ xb, const u16* __restrict__ xT, const u16* __restrict__ ub,
    const float* __restrict__ sq, const float* __restrict__ tvec, const float* __restrict__ un2,
    const float* __restrict__ maxslots, const float* __restrict__ r1in,
    const float* __restrict__ r2in, float* __restrict__ ez_part, float* __restrict__ s_part) {
  __shared__ u16 ldsw[64 * LDW];
  __shared__ float sred[4][64];
  const int tid = threadIdx.x, w = tid >> 6, lane = tid & 63;
  const int l16 = lane & 15, quad = lane >> 4;
  const int j0 = blockIdx.x * 64;
  const int ibase = blockIdx.y * 256;

  float md = 0.f;
#pragma unroll
  for (int k = 0; k < 64; ++k) md = fmaxf(md, maxslots[k * 16]);
  const float mdist = sqrtf(md);
  const float r1 = fminf(r1in[0], mdist);
  const float r2 = fminf(r2in[0], mdist);
  const float h1 = 0.5f * r1, h2 = 0.5f * r2;
  const float inv1 = 1.f / r1, inv2 = 1.f / r2;

  float sqj[4], tj[4], u2j[4];
  bf16x8 xj[4][2], uj[4][2];
#pragma unroll
  for (int jt = 0; jt < 4; ++jt) {
    int jr = j0 + jt * 16 + l16;
    sqj[jt] = sq[jr];
    tj[jt] = tvec[jr];
    u2j[jt] = un2[jr];
    xj[jt][0] = ld8(xb + jr * 64 + quad * 8);
    xj[jt][1] = ld8(xb + jr * 64 + 32 + quad * 8);
    uj[jt][0] = ld8(ub + jr * 64 + quad * 8);
    uj[jt][1] = ld8(ub + jr * 64 + 32 + quad * 8);
  }
  f32x4 zero4 = {0.f, 0.f, 0.f, 0.f};
  f32x4 acc[4];
#pragma unroll
  for (int pt = 0; pt < 4; ++pt) acc[pt] = zero4;
  float sb[4] = {0.f, 0.f, 0.f, 0.f};

  for (int s = 0; s < 4; ++s) {
    const int ib = ibase + s * 64;
    const int ir = ib + w * 16;
    bf16x8 a0 = ld8(xb + (ir + l16) * 64 + quad * 8);
    bf16x8 a1 = ld8(xb + (ir + l16) * 64 + 32 + quad * 8);
    float sqi[4];
#pragma unroll
    for (int r = 0; r < 4; ++r) sqi[r] = sq[ir + quad * 4 + r];
#pragma unroll
    for (int jt = 0; jt < 4; ++jt) {
      f32x4 gxx = zero4, gxu = zero4;
      gxx = mfma16(a0, xj[jt][0], gxx);
      gxx = mfma16(a1, xj[jt][1], gxx);
      gxu = mfma16(a0, uj[jt][0], gxu);
      gxu = mfma16(a1, uj[jt][1], gxu);
      u16x4 pk;
#pragma unroll
      for (int r = 0; r < 4; ++r) {
        float d2 = fmaxf(sqi[r] + sqj[jt] - 2.f * gxx[r], 0.f);
        float c = gxu[r] - tj[jt];
        float du2 = fmaxf(c * c * u2j[jt], 1e-6f);
        float dv = sqrtf(fmaxf(d2 - du2, 1e-6f));
        float du = sqrtf(du2);
        float wv = wfun2(dv, r1, h1, inv1) * wfun2(du, r2, h2, inv2);
        sb[jt] += wv;
        pk[r] = f2bf(wv);
      }
      *reinterpret_cast<u16x4*>(&ldsw[(jt * 16 + l16) * LDW + w * 16 + quad * 4]) = pk;
    }
    __syncthreads();
    bf16x8 aw0 = *reinterpret_cast<const bf16x8*>(&ldsw[(w * 16 + l16) * LDW + quad * 8]);
    bf16x8 aw1 = *reinterpret_cast<const bf16x8*>(&ldsw[(w * 16 + l16) * LDW + 32 + quad * 8]);
#pragma unroll
    for (int pt = 0; pt < 4; ++pt) {
      const u16* xp = xT + (pt * 16 + l16) * NROW + ib + quad * 8;
      acc[pt] = mfma16(aw0, ld8(xp), acc[pt]);
      acc[pt] = mfma16(aw1, ld8(xp + 32), acc[pt]);
    }
    __syncthreads();
  }
  float* ep = ez_part + (size_t)blockIdx.y * SLICE;
#pragma unroll
  for (int pt = 0; pt < 4; ++pt)
#pragma unroll
    for (int r = 0; r < 4; ++r)
      ep[(j0 + w * 16 + quad * 4 + r) * 64 + pt * 16 + l16] = acc[pt][r];
#pragma unroll
  for (int jt = 0; jt < 4; ++jt) {
    float v = sb[jt];
    v += __shfl_xor(v, 16);
    v += __shfl_xor(v, 32);
    if (lane < 16) sred[w][jt * 16 + lane] = v;
  }
  __syncthreads();
  if (tid < 64)
    s_part[blockIdx.y * NROW + j0 + tid] =
        sred[0][tid] + sred[1][tid] + sred[2][tid] + sred[3][tid];
}

// ---------------- finish: e_Z = reduce partials, NaN -> x ----------------
__global__ __launch_bounds__(256) void finish_kernel(const float* __restrict__ x,
                                                     const float* __restrict__ ez_part,
                                                     const float* __restrict__ s_part,
                                                     float* __restrict__ out) {
  int row = blockIdx.x * 4 + (threadIdx.x >> 6);
  int lane = threadIdx.x & 63;
  float num = 0.f, den = 0.f;
#pragma unroll
  for (int y = 0; y < NSPLIT; ++y) {
    num += ez_part[(size_t)y * SLICE + row * 64 + lane];
    den += s_part[y * NROW + row];
  }
  float xv = x[row * 64 + lane];
  float v = num / den;
  if (v != v) v = xv;
  out[row * 64 + lane] = v;
}

extern "C" void kernel_launch(void* const* d_in, const int* in_sizes, int n_in,
                              void* d_out, int out_size, void* d_ws, size_t ws_size,
                              hipStream_t stream) {
  (void)in_sizes; (void)n_in; (void)out_size;
  const float* x = (const float*)d_in[0];
  const float* r0 = (const float*)d_in[1];
  const float* r1 = (const float*)d_in[2];
  const float* r2 = (const float*)d_in[3];
  float* out = (float*)d_out;
  char* ws = (char*)d_ws;

  // workspace layout (KB offsets)
  u16* xb = (u16*)(ws);                              // 512 KB
  u16* xT = (u16*)(ws + (512 << 10));                // 512 KB
  u16* ub = (u16*)(ws + (1024 << 10));               // 512 KB
  float* sq = (float*)(ws + (1536 << 10));           // 16 KB
  float* tv = (float*)(ws + (1552 << 10));           // 16 KB
  float* u2 = (float*)(ws + (1568 << 10));           // 16 KB
  float* maxslots = (float*)(ws + (1584 << 10));     // 4 KB (zeroed)
  float* s_part_a = (float*)(ws + (1588 << 10));     // 256 KB
  float* s_part_b = (float*)(ws + (1844 << 10));     // 256 KB
  float* part = (float*)(ws + (2100 << 10));         // 16 MB (aliased mu/ez partials)
  size_t need = ((size_t)2100 << 10) + ((size_t)16 << 20);
  if (ws_size < need) return;  // loud failure if ws too small

  hipMemsetAsync(maxslots, 0, 4096, stream);
  prep_kernel<<<64, 256, 0, stream>>>(x, xb, xT, sq);
  pass1_max<<<4096, 256, 0, stream>>>(xb, sq, maxslots);
  pass2_kernel<<<dim3(64, NSPLIT), 256, 0, stream>>>(xb, xT, sq, maxslots, r0, part, s_part_a);
  finish_mu_kernel<<<1024, 256, 0, stream>>>(x, part, s_part_a, ub, u2, tv);
  pass3_kernel<<<dim3(64, NSPLIT), 256, 0, stream>>>(xb, xT, ub, sq, tv, u2, maxslots, r1, r2,
                                                     part, s_part_b);
  finish_kernel<<<1024, 256, 0, stream>>>(x, part, s_part_b, out);
}

// Round 3
// 170.789 us; speedup vs baseline: 1.3812x; 1.0814x over previous
//
#include <hip/hip_runtime.h>
#include <stdint.h>

typedef unsigned short u16;
typedef short bf16x8 __attribute__((ext_vector_type(8)));
typedef unsigned short u16x4 __attribute__((ext_vector_type(4)));
typedef float f32x4 __attribute__((ext_vector_type(4)));

#define NROW 4096
#define LDW 72        // LDS row stride (u16) for 64x64 W^T tile
#define SLICE 262144  // 4096*64 floats per partial slice
#define NSPLIT 16     // split-k over i

// round-to-nearest-even float -> bf16 bits
__device__ __forceinline__ u16 f2bf(float f) {
  uint32_t u = __float_as_uint(f);
  u = (u + 0x7fffu + ((u >> 16) & 1u)) >> 16;
  return (u16)u;
}

__device__ __forceinline__ f32x4 mfma16(bf16x8 a, bf16x8 b, f32x4 c) {
  return __builtin_amdgcn_mfma_f32_16x16x32_bf16(a, b, c, 0, 0, 0);
}

__device__ __forceinline__ bf16x8 ld8(const u16* p) {
  return *reinterpret_cast<const bf16x8*>(p);
}

// ---------------- prep: sq[i], xb, xT; also zero-init maxslots ----------------
__global__ __launch_bounds__(256) void prep_kernel(const float* __restrict__ x,
                                                   u16* __restrict__ xb, u16* __restrict__ xT,
                                                   float* __restrict__ sq,
                                                   float* __restrict__ maxslots) {
  __shared__ u16 lt[64 * 68];
  const int w = threadIdx.x >> 6, lane = threadIdx.x & 63;
  const int r0 = blockIdx.x * 64;
  if (blockIdx.x == 0 && threadIdx.x < 64) maxslots[threadIdx.x * 16] = 0.f;
#pragma unroll
  for (int rr = 0; rr < 16; ++rr) {
    int rl = w * 16 + rr;
    int row = r0 + rl;
    float v = x[row * 64 + lane];
    u16 b = f2bf(v);
    xb[row * 64 + lane] = b;
    lt[lane * 68 + rl] = b;
    float s = v * v;
#pragma unroll
    for (int o = 1; o < 64; o <<= 1) s += __shfl_xor(s, o);
    if (lane == 0) sq[row] = s;
  }
  __syncthreads();
#pragma unroll
  for (int cc = 0; cc < 16; ++cc) {
    int c = w * 16 + cc;
    xT[c * NROW + r0 + lane] = lt[c * 68 + lane];
  }
}

// ---------------- pass1: max over clamped d2; 1 atomic per block ----------------
__global__ __launch_bounds__(256) void pass1_max(const u16* __restrict__ xb,
                                                 const float* __restrict__ sq,
                                                 float* __restrict__ maxslots) {
  __shared__ float red[4];
  int w = threadIdx.x >> 6, lane = threadIdx.x & 63;
  int l16 = lane & 15, quad = lane >> 4;
  int ti = blockIdx.x & 63, tj = blockIdx.x >> 6;
  int i0 = ti * 64 + w * 16, j0 = tj * 64;
  bf16x8 a0 = ld8(xb + (i0 + l16) * 64 + quad * 8);
  bf16x8 a1 = ld8(xb + (i0 + l16) * 64 + 32 + quad * 8);
  float sqi[4];
#pragma unroll
  for (int r = 0; r < 4; ++r) sqi[r] = sq[i0 + quad * 4 + r];
  float m = 0.f;
#pragma unroll
  for (int jt = 0; jt < 4; ++jt) {
    int jr = j0 + jt * 16 + l16;
    bf16x8 b0 = ld8(xb + jr * 64 + quad * 8);
    bf16x8 b1 = ld8(xb + jr * 64 + 32 + quad * 8);
    f32x4 g = {0.f, 0.f, 0.f, 0.f};
    g = mfma16(a0, b0, g);
    g = mfma16(a1, b1, g);
    float sj = sq[jr];
#pragma unroll
    for (int r = 0; r < 4; ++r) m = fmaxf(m, fmaf(-2.f, g[r], sqi[r] + sj));
  }
  m = fmaxf(m, 0.f);
#pragma unroll
  for (int o = 1; o < 64; o <<= 1) m = fmaxf(m, __shfl_xor(m, o));
  if (lane == 0) red[w] = m;
  __syncthreads();
  if (threadIdx.x == 0) {
    m = fmaxf(fmaxf(red[0], red[1]), fmaxf(red[2], red[3]));
    atomicMax((int*)&maxslots[ti * 16], __float_as_int(m));
  }
}

// ---------------- rparams: fold 64 slots, derive weight constants ----------------
__global__ void rparams_kernel(const float* __restrict__ maxslots, const float* __restrict__ r0in,
                               const float* __restrict__ r1in, const float* __restrict__ r2in,
                               float* __restrict__ params) {
  int lane = threadIdx.x & 63;
  float m = maxslots[lane * 16];
#pragma unroll
  for (int o = 1; o < 64; o <<= 1) m = fmaxf(m, __shfl_xor(m, o));
  if (lane == 0) {
    float md = sqrtf(m);
    float r0 = fminf(r0in[0], md);
    float r1 = fminf(r1in[0], md);
    float r2 = fminf(r2in[0], md);
    params[0] = r0 * r0;
    params[1] = 1.f / (r0 * r0);
    params[2] = r1;
    params[3] = 0.5f * r1;
    params[4] = 2.f / r1;
    params[5] = r2;
    params[6] = 0.5f * r2;
    params[7] = 2.f / r2;
  }
}

// ---------------- pass2: alpha weights + mu numerator partials ----------------
__global__ __launch_bounds__(256) void pass2_kernel(
    const u16* __restrict__ xb, const u16* __restrict__ xT, const float* __restrict__ sq,
    const float* __restrict__ params, float* __restrict__ mu_part, float* __restrict__ s_part) {
  __shared__ u16 ldsw[2][64 * LDW];
  __shared__ float sred[4][64];
  const int tid = threadIdx.x, w = tid >> 6, lane = tid & 63;
  const int l16 = lane & 15, quad = lane >> 4;
  const int j0 = blockIdx.x * 64;
  const int ibase = blockIdx.y * 256;

  const float r0sq = params[0];
  const float invr0sq = params[1];

  float sqj[4];
  bf16x8 xj[4][2];
#pragma unroll
  for (int jt = 0; jt < 4; ++jt) {
    int jr = j0 + jt * 16 + l16;
    sqj[jt] = sq[jr];
    xj[jt][0] = ld8(xb + jr * 64 + quad * 8);
    xj[jt][1] = ld8(xb + jr * 64 + 32 + quad * 8);
  }
  f32x4 zero4 = {0.f, 0.f, 0.f, 0.f};
  f32x4 acc[4];
#pragma unroll
  for (int pt = 0; pt < 4; ++pt) acc[pt] = zero4;
  float sa[4] = {0.f, 0.f, 0.f, 0.f};

  for (int s = 0; s < 4; ++s) {
    u16* buf = &ldsw[s & 1][0];
    const int ib = ibase + s * 64;
    const int ir = ib + w * 16;
    bf16x8 a0 = ld8(xb + (ir + l16) * 64 + quad * 8);
    bf16x8 a1 = ld8(xb + (ir + l16) * 64 + 32 + quad * 8);
    float sqi[4];
#pragma unroll
    for (int r = 0; r < 4; ++r) sqi[r] = sq[ir + quad * 4 + r];
#pragma unroll
    for (int jt = 0; jt < 4; ++jt) {
      f32x4 g = zero4;
      g = mfma16(a0, xj[jt][0], g);
      g = mfma16(a1, xj[jt][1], g);
      u16x4 pk;
#pragma unroll
      for (int r = 0; r < 4; ++r) {
        float d2 = fmaxf(fmaf(-2.f, g[r], sqi[r] + sqj[jt]), 0.f);
        float b = fmaf(-d2, invr0sq, 1.f);
        float w1 = b * b * b;
        w1 = d2 < r0sq ? w1 : 0.f;
        sa[jt] += w1;
        pk[r] = f2bf(w1);
      }
      *reinterpret_cast<u16x4*>(&buf[(jt * 16 + l16) * LDW + w * 16 + quad * 4]) = pk;
    }
    __syncthreads();
    bf16x8 aw0 = *reinterpret_cast<const bf16x8*>(&buf[(w * 16 + l16) * LDW + quad * 8]);
    bf16x8 aw1 = *reinterpret_cast<const bf16x8*>(&buf[(w * 16 + l16) * LDW + 32 + quad * 8]);
#pragma unroll
    for (int pt = 0; pt < 4; ++pt) {
      const u16* xp = xT + (pt * 16 + l16) * NROW + ib + quad * 8;
      acc[pt] = mfma16(aw0, ld8(xp), acc[pt]);
      acc[pt] = mfma16(aw1, ld8(xp + 32), acc[pt]);
    }
  }
  float* mp = mu_part + (size_t)blockIdx.y * SLICE;
#pragma unroll
  for (int pt = 0; pt < 4; ++pt)
#pragma unroll
    for (int r = 0; r < 4; ++r)
      mp[(j0 + w * 16 + quad * 4 + r) * 64 + pt * 16 + l16] = acc[pt][r];
#pragma unroll
  for (int jt = 0; jt < 4; ++jt) {
    float v = sa[jt];
    v += __shfl_xor(v, 16);
    v += __shfl_xor(v, 32);
    if (lane < 16) sred[w][jt * 16 + lane] = v;
  }
  __syncthreads();
  if (tid < 64)
    s_part[blockIdx.y * NROW + j0 + tid] =
        sred[0][tid] + sred[1][tid] + sred[2][tid] + sred[3][tid];
}

// ---------------- finish_mu: reduce partials; U, ||U||^2, t ----------------
__global__ __launch_bounds__(256) void finish_mu_kernel(
    const float* __restrict__ x, const float* __restrict__ mu_part,
    const float* __restrict__ s_part, u16* __restrict__ ub, float* __restrict__ un2,
    float* __restrict__ tvec) {
  int row = blockIdx.x * 4 + (threadIdx.x >> 6);
  int lane = threadIdx.x & 63;
  float num = 0.f, den = 0.f;
#pragma unroll
  for (int y = 0; y < NSPLIT; ++y) {
    num += mu_part[(size_t)y * SLICE + row * 64 + lane];
    den += s_part[y * NROW + row];
  }
  float xv = x[row * 64 + lane];
  float m = num / den;
  if (m != m) m = xv;
  float U = xv - m;
  ub[row * 64 + lane] = f2bf(U);
  float a = U * U;
  float b = xv * U;
#pragma unroll
  for (int o = 1; o < 64; o <<= 1) {
    a += __shfl_xor(a, o);
    b += __shfl_xor(b, o);
  }
  if (lane == 0) {
    un2[row] = a;
    tvec[row] = b;
  }
}

// ---------------- pass3: beta weights + e_Z numerator partials ----------------
__global__ __launch_bounds__(256) void pass3_kernel(
    const u16* __restrict__ xb, const u16* __restrict__ xT, const u16* __restrict__ ub,
    const float* __restrict__ sq, const float* __restrict__ tvec, const float* __restrict__ un2,
    const float* __restrict__ params, float* __restrict__ ez_part, float* __restrict__ s_part) {
  __shared__ u16 ldsw[2][64 * LDW];
  __shared__ float sred[4][64];
  const int tid = threadIdx.x, w = tid >> 6, lane = tid & 63;
  const int l16 = lane & 15, quad = lane >> 4;
  const int j0 = blockIdx.x * 64;
  const int ibase = blockIdx.y * 256;

  const float r1v = params[2], h1 = params[3], i1x2 = params[4];
  const float r2v = params[5], h2 = params[6], i2x2 = params[7];

  float sqj[4], tj[4], u2j[4];
  bf16x8 xj[4][2], uj[4][2];
#pragma unroll
  for (int jt = 0; jt < 4; ++jt) {
    int jr = j0 + jt * 16 + l16;
    sqj[jt] = sq[jr];
    tj[jt] = tvec[jr];
    u2j[jt] = un2[jr];
    xj[jt][0] = ld8(xb + jr * 64 + quad * 8);
    xj[jt][1] = ld8(xb + jr * 64 + 32 + quad * 8);
    uj[jt][0] = ld8(ub + jr * 64 + quad * 8);
    uj[jt][1] = ld8(ub + jr * 64 + 32 + quad * 8);
  }
  f32x4 zero4 = {0.f, 0.f, 0.f, 0.f};
  f32x4 acc[4];
#pragma unroll
  for (int pt = 0; pt < 4; ++pt) acc[pt] = zero4;
  float sb[4] = {0.f, 0.f, 0.f, 0.f};

  for (int s = 0; s < 4; ++s) {
    u16* buf = &ldsw[s & 1][0];
    const int ib = ibase + s * 64;
    const int ir = ib + w * 16;
    bf16x8 a0 = ld8(xb + (ir + l16) * 64 + quad * 8);
    bf16x8 a1 = ld8(xb + (ir + l16) * 64 + 32 + quad * 8);
    float sqi[4];
#pragma unroll
    for (int r = 0; r < 4; ++r) sqi[r] = sq[ir + quad * 4 + r];
#pragma unroll
    for (int jt = 0; jt < 4; ++jt) {
      f32x4 gxx = zero4, gxu = zero4;
      gxx = mfma16(a0, xj[jt][0], gxx);
      gxx = mfma16(a1, xj[jt][1], gxx);
      gxu = mfma16(a0, uj[jt][0], gxu);
      gxu = mfma16(a1, uj[jt][1], gxu);
      u16x4 pk;
#pragma unroll
      for (int r = 0; r < 4; ++r) {
        float d2 = fmaxf(fmaf(-2.f, gxx[r], sqi[r] + sqj[jt]), 0.f);
        float c = gxu[r] - tj[jt];
        float du2 = fmaxf(c * c * u2j[jt], 1e-6f);
        float dv2 = fmaxf(d2 - du2, 1e-6f);
        float du = du2 * __builtin_amdgcn_rsqf(du2);
        float dv = dv2 * __builtin_amdgcn_rsqf(dv2);
        float t1 = fmaf(dv, i1x2, -1.f);
        float b1 = fmaf(-t1, t1, 1.f);
        float w1 = b1 * b1 * b1;
        w1 = dv < h1 ? 1.f : w1;
        w1 = dv < r1v ? w1 : 0.f;
        float t2 = fmaf(du, i2x2, -1.f);
        float b2 = fmaf(-t2, t2, 1.f);
        float w2 = b2 * b2 * b2;
        w2 = du < h2 ? 1.f : w2;
        w2 = du < r2v ? w2 : 0.f;
        float wv = w1 * w2;
        sb[jt] += wv;
        pk[r] = f2bf(wv);
      }
      *reinterpret_cast<u16x4*>(&buf[(jt * 16 + l16) * LDW + w * 16 + quad * 4]) = pk;
    }
    __syncthreads();
    bf16x8 aw0 = *reinterpret_cast<const bf16x8*>(&buf[(w * 16 + l16) * LDW + quad * 8]);
    bf16x8 aw1 = *reinterpret_cast<const bf16x8*>(&buf[(w * 16 + l16) * LDW + 32 + quad * 8]);
#pragma unroll
    for (int pt = 0; pt < 4; ++pt) {
      const u16* xp = xT + (pt * 16 + l16) * NROW + ib + quad * 8;
      acc[pt] = mfma16(aw0, ld8(xp), acc[pt]);
      acc[pt] = mfma16(aw1, ld8(xp + 32), acc[pt]);
    }
  }
  float* ep = ez_part + (size_t)blockIdx.y * SLICE;
#pragma unroll
  for (int pt = 0; pt < 4; ++pt)
#pragma unroll
    for (int r = 0; r < 4; ++r)
      ep[(j0 + w * 16 + quad * 4 + r) * 64 + pt * 16 + l16] = acc[pt][r];
#pragma unroll
  for (int jt = 0; jt < 4; ++jt) {
    float v = sb[jt];
    v += __shfl_xor(v, 16);
    v += __shfl_xor(v, 32);
    if (lane < 16) sred[w][jt * 16 + lane] = v;
  }
  __syncthreads();
  if (tid < 64)
    s_part[blockIdx.y * NROW + j0 + tid] =
        sred[0][tid] + sred[1][tid] + sred[2][tid] + sred[3][tid];
}

// ---------------- finish: e_Z = reduce partials, NaN -> x ----------------
__global__ __launch_bounds__(256) void finish_kernel(const float* __restrict__ x,
                                                     const float* __restrict__ ez_part,
                                                     const float* __restrict__ s_part,
                                                     float* __restrict__ out) {
  int row = blockIdx.x * 4 + (threadIdx.x >> 6);
  int lane = threadIdx.x & 63;
  float num = 0.f, den = 0.f;
#pragma unroll
  for (int y = 0; y < NSPLIT; ++y) {
    num += ez_part[(size_t)y * SLICE + row * 64 + lane];
    den += s_part[y * NROW + row];
  }
  float xv = x[row * 64 + lane];
  float v = num / den;
  if (v != v) v = xv;
  out[row * 64 + lane] = v;
}

extern "C" void kernel_launch(void* const* d_in, const int* in_sizes, int n_in,
                              void* d_out, int out_size, void* d_ws, size_t ws_size,
                              hipStream_t stream) {
  (void)in_sizes; (void)n_in; (void)out_size;
  const float* x = (const float*)d_in[0];
  const float* r0 = (const float*)d_in[1];
  const float* r1 = (const float*)d_in[2];
  const float* r2 = (const float*)d_in[3];
  float* out = (float*)d_out;
  char* ws = (char*)d_ws;

  u16* xb = (u16*)(ws);                              // 512 KB
  u16* xT = (u16*)(ws + (512 << 10));                // 512 KB
  u16* ub = (u16*)(ws + (1024 << 10));               // 512 KB
  float* sq = (float*)(ws + (1536 << 10));           // 16 KB
  float* tv = (float*)(ws + (1552 << 10));           // 16 KB
  float* u2 = (float*)(ws + (1568 << 10));           // 16 KB
  float* maxslots = (float*)(ws + (1584 << 10));     // 4 KB
  float* params = (float*)(ws + (1588 << 10));       // 4 KB
  float* s_part_a = (float*)(ws + (1592 << 10));     // 256 KB
  float* s_part_b = (float*)(ws + (1848 << 10));     // 256 KB
  float* part = (float*)(ws + (2104 << 10));         // 16 MB (aliased mu/ez partials)
  size_t need = ((size_t)2104 << 10) + ((size_t)16 << 20);
  if (ws_size < need) return;

  prep_kernel<<<64, 256, 0, stream>>>(x, xb, xT, sq, maxslots);
  pass1_max<<<4096, 256, 0, stream>>>(xb, sq, maxslots);
  rparams_kernel<<<1, 64, 0, stream>>>(maxslots, r0, r1, r2, params);
  pass2_kernel<<<dim3(64, NSPLIT), 256, 0, stream>>>(xb, xT, sq, params, part, s_part_a);
  finish_mu_kernel<<<1024, 256, 0, stream>>>(x, part, s_part_a, ub, u2, tv);
  pass3_kernel<<<dim3(64, NSPLIT), 256, 0, stream>>>(xb, xT, ub, sq, tv, u2, params, part,
                                                     s_part_b);
  finish_kernel<<<1024, 256, 0, stream>>>(x, part, s_part_b, out);
}